// Round 3
// baseline (11.890 us; speedup 1.0000x reference)
//
#include <hip/hip_runtime.h>
#include <hip/hip_bf16.h>

// out[b, j] = tokens[b, idx[b, j], j]
// tokens: [B=64, S=512, E=1024] fp32,  idx: [B, E] int32,  out: [B, E] fp32
//
// Final form: 1 element/thread, 65536 threads. idx load and out store fully
// coalesced; one scattered gather per thread. Shape hardcoded so address math
// is shifts/masks only. Measured equal (within noise) to a 4-elem/thread
// int4/float4 variant — dur_us is pinned at the ~10us launch-overhead floor
// (device-side data floor is ~1.4us), so simplest/fastest-measured wins.

__global__ void __launch_bounds__(256)
embrace_gather_kernel(const float* __restrict__ tokens,
                      const int* __restrict__ idx,
                      float* __restrict__ out) {
    int i = blockIdx.x * 256 + threadIdx.x;    // 0 .. 65535 = b*1024 + j
    int b = i >> 10;                           // E = 1024
    int j = i & 1023;
    int s = idx[i];                            // coalesced 4B
    // element offset: (b*512 + s)*1024 + j = (b<<19) + (s<<10) + j
    out[i] = tokens[((size_t)b << 19) + ((size_t)s << 10) + j];   // gather
}

extern "C" void kernel_launch(void* const* d_in, const int* in_sizes, int n_in,
                              void* d_out, int out_size, void* d_ws, size_t ws_size,
                              hipStream_t stream) {
    const float* tokens = (const float*)d_in[0];   // [B, S, E]
    const int*   idx    = (const int*)d_in[1];     // [B, E]
    float*       out    = (float*)d_out;           // [B, E]

    const int block = 256;
    const int grid  = out_size / block;            // 65536 / 256 = 256
    embrace_gather_kernel<<<grid, block, 0, stream>>>(tokens, idx, out);
}